// Round 6
// baseline (679.988 us; speedup 1.0000x reference)
//
#include <hip/hip_runtime.h>
#include <math.h>

#define NN 50000
#define NE 800000
#define F_IN 11
#define HID 128
#define NEG_SLOPE 0.2f

typedef __attribute__((ext_vector_type(8))) short short8;
typedef __attribute__((ext_vector_type(4))) float f32x4;

__device__ __forceinline__ float bf2f(ushort u) {
  return __uint_as_float(((unsigned)u) << 16);
}
__device__ __forceinline__ ushort f2bf(float f) {
  unsigned u = __float_as_uint(f);
  return (ushort)((u + 0x7fff + ((u >> 16) & 1)) >> 16);
}
__device__ __forceinline__ float lrelu(float x) { return x > 0.f ? x : NEG_SLOPE * x; }
__device__ __forceinline__ float elu1(float x) { return x > 0.f ? x : expm1f(x); }

// finite "-inf": online-softmax merges of empty lanes must never form inf-inf=NaN
#define MNEG (-1e30f)

// order own-wave ds_writes before cross-lane ds_reads (no cross-wave sync needed)
__device__ __forceinline__ void wave_fence() {
  asm volatile("s_waitcnt lgkmcnt(0)" ::: "memory");
}

#define AS1 __attribute__((address_space(1)))
#define AS3 __attribute__((address_space(3)))

// ---------- CSR build ----------
__global__ void k_deg(const int* __restrict__ ei, int* __restrict__ deg) {
  int e = blockIdx.x * blockDim.x + threadIdx.x;
  if (e < NE) atomicAdd(&deg[ei[NE + e]], 1);
}

__global__ void k_scan(const int* __restrict__ deg, int* __restrict__ row_ptr,
                       int* __restrict__ cursor) {
  const int T = 1024;
  const int CH = (NN + T - 1) / T;
  __shared__ int ssum[T];
  int t = threadIdx.x;
  int base = t * CH;
  int s = 0;
  for (int i = 0; i < CH; i++) {
    int idx = base + i;
    if (idx < NN) s += deg[idx];
  }
  ssum[t] = s;
  __syncthreads();
  for (int off = 1; off < T; off <<= 1) {
    int v = (t >= off) ? ssum[t - off] : 0;
    __syncthreads();
    ssum[t] += v;
    __syncthreads();
  }
  int run = ssum[t] - s;
  for (int i = 0; i < CH; i++) {
    int idx = base + i;
    if (idx < NN) {
      row_ptr[idx] = run;
      cursor[idx] = run;
      run += deg[idx];
    }
  }
  if (t == 0) row_ptr[NN] = ssum[T - 1];
}

__global__ void k_scatter(const int* __restrict__ ei, int* __restrict__ cursor,
                          int* __restrict__ csr_src) {
  int e = blockIdx.x * blockDim.x + threadIdx.x;
  if (e < NE) {
    int d = ei[NE + e];
    int pos = atomicAdd(&cursor[d], 1);
    csr_src[pos] = ei[e];
  }
}

// ---------- weight transpose + bf16 convert: Wt[n][k] = W[k][n] ----------
__global__ void k_wt(const float* __restrict__ W, ushort* __restrict__ Wt, int K, int N) {
  __shared__ float tl[32][33];
  int bn = blockIdx.x * 32, bk = blockIdx.y * 32;
  int tx = threadIdx.x & 31, ty = threadIdx.x >> 5;
  for (int i = ty; i < 32; i += 8) tl[i][tx] = W[(size_t)(bk + i) * N + bn + tx];
  __syncthreads();
  for (int i = ty; i < 32; i += 8)
    Wt[(size_t)(bn + i) * K + bk + tx] = f2bf(tl[tx][i]);
}

// ---------- layer 1: collapsed attention vectors v_s/v_d[k][h] ----------
__global__ void k_vsd(const float* __restrict__ W1, const float* __restrict__ as1,
                      const float* __restrict__ ad1, float* __restrict__ vs,
                      float* __restrict__ vd) {
  int t = threadIdx.x;  // 128, 88 active
  if (t >= 88) return;
  int side = t & 1, kh = t >> 1;  // kh = k*4+h
  int k = kh >> 2, h = kh & 3;
  const float* av = side ? ad1 : as1;
  float s = 0.f;
  for (int c = 0; c < HID; c++) s += W1[k * 512 + h * HID + c] * av[h * HID + c];
  (side ? vd : vs)[kh] = s;
}

// ---------- layer 1: per-node attention scores from raw x ----------
__global__ void k_ax(const float* __restrict__ x, const float* __restrict__ vs,
                     const float* __restrict__ vd, float* __restrict__ asrc,
                     float* __restrict__ adst) {
  int n = blockIdx.x * blockDim.x + threadIdx.x;
  if (n >= NN) return;
  float xr[F_IN];
#pragma unroll
  for (int k = 0; k < F_IN; k++) xr[k] = x[n * F_IN + k];
  float s[4] = {}, dd[4] = {};
#pragma unroll
  for (int k = 0; k < F_IN; k++)
#pragma unroll
    for (int h = 0; h < 4; h++) {
      s[h] += xr[k] * vs[k * 4 + h];
      dd[h] += xr[k] * vd[k * 4 + h];
    }
  *(f32x4*)(asrc + n * 4) = f32x4{s[0], s[1], s[2], s[3]};
  *(f32x4*)(adst + n * 4) = f32x4{dd[0], dd[1], dd[2], dd[3]};
}

// ---------- layer 1: aggregate RAW x (11-dim, L2-resident) -> P[n][4][11] ----------
__global__ __launch_bounds__(256) void k_aggpre(
    const float* __restrict__ x, const float* __restrict__ asrc,
    const float* __restrict__ adst, const int* __restrict__ row_ptr,
    const int* __restrict__ csr_src, float* __restrict__ P) {
  const int CAP = 64;
  __shared__ int src_c[4][CAP];
  __shared__ float ea[4][CAP * 4];
  int t = threadIdx.x, lane = t & 63, wv = t >> 6;
  int d = blockIdx.x * 4 + wv;
  int start = row_ptr[d], deg = row_ptr[d + 1] - start;
  int dcap = min(deg, CAP);
  for (int i = lane; i < dcap; i += 64) src_c[wv][i] = csr_src[start + i];
  wave_fence();
  int hh = lane & 3;
  float adh = adst[d * 4 + hh];
  float m = MNEG, s = 0.f;
  int deg4 = deg * 4;
  for (int i = lane; i < deg4; i += 64) {
    int k = i >> 2;
    int sn = (k < CAP) ? src_c[wv][k] : csr_src[start + k];
    float v = lrelu(asrc[sn * 4 + hh] + adh);
    if (k < CAP) ea[wv][i] = v;
    float nm = fmaxf(m, v);
    s = s * __expf(m - nm) + __expf(v - nm);
    m = nm;
  }
#pragma unroll
  for (int off = 4; off < 64; off <<= 1) {
    float m2 = __shfl_xor(m, off);
    float s2 = __shfl_xor(s, off);
    float nm = fmaxf(m, m2);
    s = s * __expf(m - nm) + s2 * __expf(m2 - nm);
    m = nm;
  }
  float sinv = (s > 0.f) ? 1.f / s : 0.f;
  int dc4 = dcap * 4;
  for (int i = lane; i < dc4; i += 64) ea[wv][i] = __expf(ea[wv][i] - m) * sinv;
  wave_fence();
  int hq = lane / F_IN;
  int k = lane - hq * F_IN;
  int h = hq & 3;
  float mh = __shfl(m, h), sih = __shfl(sinv, h);
  float adh2 = adst[d * 4 + h];
  float acc = 0.f;
  for (int e = 0; e < deg; e++) {
    int sn;
    float a;
    if (e < CAP) {
      sn = src_c[wv][e];
      a = ea[wv][e * 4 + h];
    } else {
      sn = csr_src[start + e];
      a = __expf(lrelu(asrc[sn * 4 + h] + adh2) - mh) * sih;
    }
    acc += a * x[sn * F_IN + k];
  }
  if (lane < 44) P[(size_t)d * 44 + lane] = acc;
}

// ---------- layer 1: out = elu(P @ W1 + b1) ----------
__global__ __launch_bounds__(256) void k_gemm_l1(
    const float* __restrict__ P, const float* __restrict__ W1,
    const float* __restrict__ b1, ushort* __restrict__ out) {
  __shared__ float sW[F_IN * 512];
  __shared__ float sP[16][44];
  int t = threadIdx.x;
  for (int i = t; i < F_IN * 512; i += 256) sW[i] = W1[i];
  int n0 = blockIdx.x * 16;
  for (int i = t; i < 16 * 44; i += 256)
    sP[i / 44][i % 44] = P[(size_t)(n0 + i / 44) * 44 + (i % 44)];
  __syncthreads();
  int j0 = 2 * t;
  int h = j0 >> 7;
  float b0 = b1[j0], bb = b1[j0 + 1];
  float w0[F_IN], w1v[F_IN];
#pragma unroll
  for (int k = 0; k < F_IN; k++) {
    w0[k] = sW[k * 512 + j0];
    w1v[k] = sW[k * 512 + j0 + 1];
  }
  for (int nn = 0; nn < 16; nn++) {
    float a0 = b0, a1 = bb;
#pragma unroll
    for (int k = 0; k < F_IN; k++) {
      float pv = sP[nn][h * F_IN + k];
      a0 += pv * w0[k];
      a1 += pv * w1v[k];
    }
    a0 = elu1(a0);
    a1 = elu1(a1);
    unsigned pk = (unsigned)f2bf(a0) | ((unsigned)f2bf(a1) << 16);
    *(unsigned*)(out + (size_t)(n0 + nn) * 512 + j0) = pk;
  }
}

// ---------- bf16 MFMA GEMM + fused alpha epilogue ----------
// C[M,N] = A[M,K] @ Bt[N,K]^T ; per block also emits
// asrc[row,hy] = sum_c C[row][hy*128+c]*a_src[hy,c]  (hy = col-block = head)
// XCD-chunked bijective swizzle (m204) on a 1D grid.
#define TM 128
#define TN 128
#define TK 64
template <int H>
__global__ __launch_bounds__(256) void k_mfma(
    const ushort* __restrict__ A, const ushort* __restrict__ Bt,
    ushort* __restrict__ C, const float* __restrict__ a_srcv,
    const float* __restrict__ a_dstv, float* __restrict__ asrc,
    float* __restrict__ adst, int M, int N, int K) {
  __shared__ ushort lds[TM * TK + TN * TK];
  __shared__ float sal[128][2], sad[128][2];
  ushort* As = lds;
  ushort* Bs = lds + TM * TK;
  int tid = threadIdx.x;
  int lane = tid & 63, wv = tid >> 6;
  int wr = wv >> 1, wc = wv & 1;
  // bijective XCD-chunk swizzle: contiguous logical chunk per XCD
  int nwg = gridDim.x;
  int q = nwg >> 3, rr = nwg & 7;
  int xcd = blockIdx.x & 7, off8 = blockIdx.x >> 3;
  int lid = (xcd < rr ? xcd * (q + 1) : rr * (q + 1) + (xcd - rr) * q) + off8;
  int bm = lid / H, hy = lid - bm * H;  // consecutive lid share bm (A-panel reuse in L2)
  int bm0 = bm * TM, bn0 = hy * TN;
  int l15 = lane & 15, l4 = lane >> 4;
  f32x4 acc[4][4] = {};
  for (int k0 = 0; k0 < K; k0 += TK) {
#pragma unroll
    for (int it = 0; it < 4; ++it) {
      int chunk = it * 4 + wv;
      int pbase = chunk * 1024;
      int p = pbase + lane * 16;
      int prow = p >> 7;
      int lblk = ((p >> 4) & 7) ^ (prow & 7);
      int gr = bm0 + prow;
      gr = gr < M ? gr : M - 1;
      __builtin_amdgcn_global_load_lds(
          (const AS1 void*)(A + (size_t)gr * K + (k0 + lblk * 8)),
          (AS3 void*)((char*)As + pbase), 16, 0, 0);
      int gb = bn0 + prow;
      __builtin_amdgcn_global_load_lds(
          (const AS1 void*)(Bt + (size_t)gb * K + (k0 + lblk * 8)),
          (AS3 void*)((char*)Bs + pbase), 16, 0, 0);
    }
    __syncthreads();
#pragma unroll
    for (int kk = 0; kk < 2; ++kk) {
      int cb = kk * 4 + l4;
      short8 af[4], bfr[4];
#pragma unroll
      for (int m = 0; m < 4; ++m) {
        int row = wr * 64 + m * 16 + l15;
        af[m] = *(const short8*)((const char*)As + row * 128 + ((cb ^ (row & 7)) << 4));
      }
#pragma unroll
      for (int n = 0; n < 4; ++n) {
        int row = wc * 64 + n * 16 + l15;
        bfr[n] = *(const short8*)((const char*)Bs + row * 128 + ((cb ^ (row & 7)) << 4));
      }
#pragma unroll
      for (int m = 0; m < 4; ++m)
#pragma unroll
        for (int n = 0; n < 4; ++n)
          acc[m][n] = __builtin_amdgcn_mfma_f32_16x16x32_bf16(af[m], bfr[n], acc[m][n], 0, 0, 0);
    }
    __syncthreads();
  }
  // C write (bf16)
#pragma unroll
  for (int m = 0; m < 4; ++m) {
#pragma unroll
    for (int r = 0; r < 4; ++r) {
      int row = bm0 + wr * 64 + m * 16 + l4 * 4 + r;
      if (row < M) {
#pragma unroll
        for (int n = 0; n < 4; ++n) {
          int col = bn0 + wc * 64 + n * 16 + l15;
          C[(size_t)row * N + col] = f2bf(acc[m][n][r]);
        }
      }
    }
  }
  // fused alpha: per-lane partial over this wave's 64 cols, reduce over l15,
  // merge wc pair via LDS, store asrc/adst for this block's 128 rows x head hy
  float asv[4], adv[4];
#pragma unroll
  for (int n = 0; n < 4; ++n) {
    int c = hy * 128 + wc * 64 + n * 16 + l15;
    asv[n] = a_srcv[c];
    adv[n] = a_dstv[c];
  }
#pragma unroll
  for (int m = 0; m < 4; ++m) {
#pragma unroll
    for (int r = 0; r < 4; ++r) {
      float s1 = 0.f, s2 = 0.f;
#pragma unroll
      for (int n = 0; n < 4; ++n) {
        float cv = acc[m][n][r];
        s1 += cv * asv[n];
        s2 += cv * adv[n];
      }
#pragma unroll
      for (int off = 1; off < 16; off <<= 1) {
        s1 += __shfl_xor(s1, off);
        s2 += __shfl_xor(s2, off);
      }
      if (l15 == 0) {
        int rb = wr * 64 + m * 16 + l4 * 4 + r;
        sal[rb][wc] = s1;
        sad[rb][wc] = s2;
      }
    }
  }
  __syncthreads();
  if (tid < 128) {
    int gr = bm0 + tid;
    if (gr < M) {
      asrc[gr * H + hy] = sal[tid][0] + sal[tid][1];
      adst[gr * H + hy] = sad[tid][0] + sad[tid][1];
    }
  }
}

// ---------- layer-2 aggregate: wave-per-node, H=4, unroll-2 gather ----------
__global__ __launch_bounds__(256) void k_agg4w(
    const ushort* __restrict__ h, const float* __restrict__ asrc,
    const float* __restrict__ adst, const int* __restrict__ row_ptr,
    const int* __restrict__ csr_src, const float* __restrict__ bias,
    ushort* __restrict__ out) {
  const int CAP = 64;
  __shared__ int src_c[4][CAP];
  __shared__ float ea[4][CAP * 4];
  int t = threadIdx.x, lane = t & 63, wv = t >> 6;
  int d = blockIdx.x * 4 + wv;
  int start = row_ptr[d], deg = row_ptr[d + 1] - start;
  int dcap = min(deg, CAP);
  for (int i = lane; i < dcap; i += 64) src_c[wv][i] = csr_src[start + i];
  wave_fence();
  int hh = lane & 3;
  float adh = adst[d * 4 + hh];
  float m = MNEG, s = 0.f;
  int deg4 = deg * 4;
  for (int i = lane; i < deg4; i += 64) {
    int k = i >> 2;
    int sn = (k < CAP) ? src_c[wv][k] : csr_src[start + k];
    float v = lrelu(asrc[sn * 4 + hh] + adh);
    if (k < CAP) ea[wv][i] = v;
    float nm = fmaxf(m, v);
    s = s * __expf(m - nm) + __expf(v - nm);
    m = nm;
  }
#pragma unroll
  for (int off = 4; off < 64; off <<= 1) {
    float m2 = __shfl_xor(m, off);
    float s2 = __shfl_xor(s, off);
    float nm = fmaxf(m, m2);
    s = s * __expf(m - nm) + s2 * __expf(m2 - nm);
    m = nm;
  }
  float sinv = (s > 0.f) ? 1.f / s : 0.f;
  int dc4 = dcap * 4;
  for (int i = lane; i < dc4; i += 64) ea[wv][i] = __expf(ea[wv][i] - m) * sinv;
  wave_fence();
  int hl = lane >> 4;
  float mh = __shfl(m, hl), sih = __shfl(sinv, hl);
  float adh2 = adst[d * 4 + hl];
  float acc0[8] = {}, acc1[8] = {};
  int k = 0;
  for (; k + 2 <= deg; k += 2) {
    int sn0, sn1;
    float a0, a1;
    if (k < CAP) {
      sn0 = src_c[wv][k];
      a0 = ea[wv][k * 4 + hl];
    } else {
      sn0 = csr_src[start + k];
      a0 = __expf(lrelu(asrc[sn0 * 4 + hl] + adh2) - mh) * sih;
    }
    if (k + 1 < CAP) {
      sn1 = src_c[wv][k + 1];
      a1 = ea[wv][(k + 1) * 4 + hl];
    } else {
      sn1 = csr_src[start + k + 1];
      a1 = __expf(lrelu(asrc[sn1 * 4 + hl] + adh2) - mh) * sih;
    }
    short8 v0 = *(const short8*)(h + (size_t)sn0 * 512 + lane * 8);
    short8 v1 = *(const short8*)(h + (size_t)sn1 * 512 + lane * 8);
#pragma unroll
    for (int j = 0; j < 8; j++) acc0[j] += a0 * bf2f((ushort)v0[j]);
#pragma unroll
    for (int j = 0; j < 8; j++) acc1[j] += a1 * bf2f((ushort)v1[j]);
  }
  if (k < deg) {
    int sn;
    float a;
    if (k < CAP) {
      sn = src_c[wv][k];
      a = ea[wv][k * 4 + hl];
    } else {
      sn = csr_src[start + k];
      a = __expf(lrelu(asrc[sn * 4 + hl] + adh2) - mh) * sih;
    }
    short8 v0 = *(const short8*)(h + (size_t)sn * 512 + lane * 8);
#pragma unroll
    for (int j = 0; j < 8; j++) acc0[j] += a * bf2f((ushort)v0[j]);
  }
  const float* bp = bias + lane * 8;
  unsigned pk[4];
#pragma unroll
  for (int j = 0; j < 4; j++) {
    float o0 = elu1(acc0[2 * j] + acc1[2 * j] + bp[2 * j]);
    float o1 = elu1(acc0[2 * j + 1] + acc1[2 * j + 1] + bp[2 * j + 1]);
    pk[j] = (unsigned)f2bf(o0) | ((unsigned)f2bf(o1) << 16);
  }
  *(uint4*)(out + (size_t)d * 512 + lane * 8) = make_uint4(pk[0], pk[1], pk[2], pk[3]);
}

// ---------- layer-3 aggregate: wave-per-node, H=1, unroll-2 gather ----------
__global__ __launch_bounds__(256) void k_agg1w(
    const ushort* __restrict__ h, const float* __restrict__ asrc,
    const float* __restrict__ adst, const int* __restrict__ row_ptr,
    const int* __restrict__ csr_src, const float* __restrict__ bias,
    ushort* __restrict__ out) {
  const int CAP = 64;
  __shared__ int src_c[4][CAP];
  __shared__ float ea[4][CAP];
  int t = threadIdx.x, lane = t & 63, wv = t >> 6;
  int d = blockIdx.x * 4 + wv;
  int start = row_ptr[d], deg = row_ptr[d + 1] - start;
  int dcap = min(deg, CAP);
  for (int i = lane; i < dcap; i += 64) src_c[wv][i] = csr_src[start + i];
  wave_fence();
  float adh = adst[d];
  float m = MNEG, s = 0.f;
  for (int i = lane; i < deg; i += 64) {
    int sn = (i < CAP) ? src_c[wv][i] : csr_src[start + i];
    float v = lrelu(asrc[sn] + adh);
    if (i < CAP) ea[wv][i] = v;
    float nm = fmaxf(m, v);
    s = s * __expf(m - nm) + __expf(v - nm);
    m = nm;
  }
#pragma unroll
  for (int off = 1; off < 64; off <<= 1) {
    float m2 = __shfl_xor(m, off);
    float s2 = __shfl_xor(s, off);
    float nm = fmaxf(m, m2);
    s = s * __expf(m - nm) + s2 * __expf(m2 - nm);
    m = nm;
  }
  float sinv = (s > 0.f) ? 1.f / s : 0.f;
  for (int i = lane; i < dcap; i += 64) ea[wv][i] = __expf(ea[wv][i] - m) * sinv;
  wave_fence();
  float a00 = 0.f, a01 = 0.f, a10 = 0.f, a11 = 0.f;
  int k = 0;
  for (; k + 2 <= deg; k += 2) {
    int sn0, sn1;
    float w0, w1;
    if (k < CAP) {
      sn0 = src_c[wv][k];
      w0 = ea[wv][k];
    } else {
      sn0 = csr_src[start + k];
      w0 = __expf(lrelu(asrc[sn0] + adh) - m) * sinv;
    }
    if (k + 1 < CAP) {
      sn1 = src_c[wv][k + 1];
      w1 = ea[wv][k + 1];
    } else {
      sn1 = csr_src[start + k + 1];
      w1 = __expf(lrelu(asrc[sn1] + adh) - m) * sinv;
    }
    unsigned h0 = *(const unsigned*)(h + (size_t)sn0 * 128 + lane * 2);
    unsigned h1 = *(const unsigned*)(h + (size_t)sn1 * 128 + lane * 2);
    a00 += w0 * bf2f((ushort)(h0 & 0xffff));
    a01 += w0 * bf2f((ushort)(h0 >> 16));
    a10 += w1 * bf2f((ushort)(h1 & 0xffff));
    a11 += w1 * bf2f((ushort)(h1 >> 16));
  }
  if (k < deg) {
    int sn;
    float w0;
    if (k < CAP) {
      sn = src_c[wv][k];
      w0 = ea[wv][k];
    } else {
      sn = csr_src[start + k];
      w0 = __expf(lrelu(asrc[sn] + adh) - m) * sinv;
    }
    unsigned h0 = *(const unsigned*)(h + (size_t)sn * 128 + lane * 2);
    a00 += w0 * bf2f((ushort)(h0 & 0xffff));
    a01 += w0 * bf2f((ushort)(h0 >> 16));
  }
  float o0 = a00 + a10 + bias[lane * 2];
  float o1 = a01 + a11 + bias[lane * 2 + 1];
  unsigned pk = (unsigned)f2bf(o0) | ((unsigned)f2bf(o1) << 16);
  *(unsigned*)(out + (size_t)d * 128 + lane * 2) = pk;
}

// ---------- graph mean + heads ----------
__global__ __launch_bounds__(256) void k_colsum(const ushort* __restrict__ h3,
                                                float* __restrict__ gsum) {
  __shared__ float partial[16 * 128];
  int t = threadIdx.x;
  int rg = t >> 4, cl = t & 15;
  int nb = gridDim.x;
  int per = (NN + nb - 1) / nb;
  int r0 = blockIdx.x * per, r1 = min(NN, r0 + per);
  float acc[8] = {};
  for (int r = r0 + rg; r < r1; r += 16) {
    short8 hv = *(const short8*)(h3 + (size_t)r * 128 + cl * 8);
#pragma unroll
    for (int j = 0; j < 8; j++) acc[j] += bf2f((ushort)hv[j]);
  }
#pragma unroll
  for (int j = 0; j < 8; j++) partial[rg * 128 + cl * 8 + j] = acc[j];
  __syncthreads();
  if (t < 128) {
    float s = 0.f;
    for (int q = 0; q < 16; q++) s += partial[q * 128 + t];
    atomicAdd(&gsum[t], s);
  }
}

__global__ void k_head(const float* __restrict__ gsum, const ushort* __restrict__ h3,
                       const int* __restrict__ curp, const float* __restrict__ pw1,
                       const float* __restrict__ pb1, const float* __restrict__ pw2,
                       const float* __restrict__ pb2, const float* __restrict__ vw1,
                       const float* __restrict__ vb1, const float* __restrict__ vw2,
                       const float* __restrict__ vb2, float* __restrict__ outp) {
  __shared__ float comb[HID], ph[HID], vh[HID];
  int t = threadIdx.x;  // 128
  int cur = curp[0];
  comb[t] = gsum[t] * (1.f / NN) + bf2f(h3[(size_t)cur * HID + t]);
  __syncthreads();
  float accp = pb1[t], accv = vb1[t];
  for (int k = 0; k < HID; k++) {
    float cv = comb[k];
    accp += cv * pw1[k * HID + t];
    accv += cv * vw1[k * HID + t];
  }
  ph[t] = fmaxf(accp, 0.f);
  vh[t] = fmaxf(accv, 0.f);
  __syncthreads();
  if (t < 6) {
    float a = pb2[t];
    for (int k = 0; k < HID; k++) a += ph[k] * pw2[k * 6 + t];
    outp[t] = a;
  }
  if (t == 6) {
    float a = vb2[0];
    for (int k = 0; k < HID; k++) a += vh[k] * vw2[k];
    outp[6] = a;
  }
}

extern "C" void kernel_launch(void* const* d_in, const int* in_sizes, int n_in,
                              void* d_out, int out_size, void* d_ws, size_t ws_size,
                              hipStream_t stream) {
  const float* x = (const float*)d_in[0];
  const int* ei = (const int*)d_in[1];
  const int* cur = (const int*)d_in[2];
  const float* W1 = (const float*)d_in[3];
  const float* as1 = (const float*)d_in[4];
  const float* ad1 = (const float*)d_in[5];
  const float* b1 = (const float*)d_in[6];
  const float* W2 = (const float*)d_in[7];
  const float* as2 = (const float*)d_in[8];
  const float* ad2 = (const float*)d_in[9];
  const float* b2 = (const float*)d_in[10];
  const float* W3 = (const float*)d_in[11];
  const float* as3 = (const float*)d_in[12];
  const float* ad3 = (const float*)d_in[13];
  const float* b3 = (const float*)d_in[14];
  const float* pw1 = (const float*)d_in[15];
  const float* pb1 = (const float*)d_in[16];
  const float* pw2 = (const float*)d_in[17];
  const float* pb2 = (const float*)d_in[18];
  const float* vw1 = (const float*)d_in[19];
  const float* vb1 = (const float*)d_in[20];
  const float* vw2 = (const float*)d_in[21];
  const float* vb2 = (const float*)d_in[22];
  float* out = (float*)d_out;

  char* w = (char*)d_ws;
  ushort* G = (ushort*)w;    w += (size_t)NN * 512 * 2;
  ushort* Abuf = (ushort*)w; w += (size_t)NN * 512 * 2;
  ushort* Wt2 = (ushort*)w;  w += (size_t)512 * 512 * 2;
  ushort* Wt3 = (ushort*)w;  w += (size_t)128 * 512 * 2;
  float* P = (float*)w;      w += (size_t)NN * 44 * 4;
  float* asrc = (float*)w;   w += (size_t)NN * 4 * 4;
  float* adst = (float*)w;   w += (size_t)NN * 4 * 4;
  int* deg = (int*)w;        w += (size_t)NN * 4;
  int* cursor = (int*)w;     w += (size_t)NN * 4;
  int* row_ptr = (int*)w;    w += (size_t)(NN + 1) * 4;
  int* csr_src = (int*)w;    w += (size_t)NE * 4;
  float* gsum = (float*)w;   w += (size_t)HID * 4;
  float* vs = (float*)w;     w += 44 * 4;
  float* vd = (float*)w;     w += 44 * 4;

  hipMemsetAsync(deg, 0, NN * 4, stream);
  hipMemsetAsync(gsum, 0, HID * 4, stream);

  k_deg<<<(NE + 255) / 256, 256, 0, stream>>>(ei, deg);
  k_scan<<<1, 1024, 0, stream>>>(deg, row_ptr, cursor);
  k_scatter<<<(NE + 255) / 256, 256, 0, stream>>>(ei, cursor, csr_src);

  k_wt<<<dim3(512 / 32, 512 / 32), 256, 0, stream>>>(W2, Wt2, 512, 512);
  k_wt<<<dim3(128 / 32, 512 / 32), 256, 0, stream>>>(W3, Wt3, 512, 128);

  const int GB = (NN + TM - 1) / TM;  // 391

  // Layer 1 (pre-aggregation trick: aggregate raw x, then GEMM)
  k_vsd<<<1, 128, 0, stream>>>(W1, as1, ad1, vs, vd);
  k_ax<<<(NN + 255) / 256, 256, 0, stream>>>(x, vs, vd, asrc, adst);
  k_aggpre<<<NN / 4, 256, 0, stream>>>(x, asrc, adst, row_ptr, csr_src, P);
  k_gemm_l1<<<NN / 16, 256, 0, stream>>>(P, W1, b1, Abuf);

  // Layer 2: bf16 MFMA + fused alpha, then wave-per-node aggregate
  k_mfma<4><<<GB * 4, 256, 0, stream>>>(Abuf, Wt2, G, as2, ad2, asrc, adst, NN, 512, 512);
  k_agg4w<<<NN / 4, 256, 0, stream>>>(G, asrc, adst, row_ptr, csr_src, b2, Abuf);

  // Layer 3: bf16 MFMA + fused alpha, then wave-per-node aggregate
  k_mfma<1><<<GB, 256, 0, stream>>>(Abuf, Wt3, G, as3, ad3, asrc, adst, NN, 128, 512);
  k_agg1w<<<NN / 4, 256, 0, stream>>>(G, asrc, adst, row_ptr, csr_src, b3, Abuf);

  // Heads
  k_colsum<<<256, 256, 0, stream>>>(Abuf, gsum);
  k_head<<<1, 128, 0, stream>>>(gsum, Abuf, cur, pw1, pb1, pw2, pb2, vw1, vb1, vw2, vb2, out);
}

// Round 7
// 671.563 us; speedup vs baseline: 1.0125x; 1.0125x over previous
//
#include <hip/hip_runtime.h>
#include <math.h>

#define NN 50000
#define NE 800000
#define F_IN 11
#define HID 128
#define NEG_SLOPE 0.2f

typedef __attribute__((ext_vector_type(8))) short short8;
typedef __attribute__((ext_vector_type(4))) float f32x4;

__device__ __forceinline__ float bf2f(ushort u) {
  return __uint_as_float(((unsigned)u) << 16);
}
__device__ __forceinline__ ushort f2bf(float f) {
  unsigned u = __float_as_uint(f);
  return (ushort)((u + 0x7fff + ((u >> 16) & 1)) >> 16);
}
__device__ __forceinline__ float lrelu(float x) { return x > 0.f ? x : NEG_SLOPE * x; }
__device__ __forceinline__ float elu1(float x) { return x > 0.f ? x : expm1f(x); }

// finite "-inf": online-softmax merges of empty lanes must never form inf-inf=NaN
#define MNEG (-1e30f)

// order own-wave ds_writes before cross-lane ds_reads (no cross-wave sync needed)
__device__ __forceinline__ void wave_fence() {
  asm volatile("s_waitcnt lgkmcnt(0)" ::: "memory");
}

#define AS1 __attribute__((address_space(1)))
#define AS3 __attribute__((address_space(3)))

// ---------- CSR build ----------
__global__ void k_deg(const int* __restrict__ ei, int* __restrict__ deg) {
  int e = blockIdx.x * blockDim.x + threadIdx.x;
  if (e < NE) atomicAdd(&deg[ei[NE + e]], 1);
}

__global__ void k_scan(const int* __restrict__ deg, int* __restrict__ row_ptr,
                       int* __restrict__ cursor) {
  const int T = 1024;
  const int CH = (NN + T - 1) / T;
  __shared__ int ssum[T];
  int t = threadIdx.x;
  int base = t * CH;
  int s = 0;
  for (int i = 0; i < CH; i++) {
    int idx = base + i;
    if (idx < NN) s += deg[idx];
  }
  ssum[t] = s;
  __syncthreads();
  for (int off = 1; off < T; off <<= 1) {
    int v = (t >= off) ? ssum[t - off] : 0;
    __syncthreads();
    ssum[t] += v;
    __syncthreads();
  }
  int run = ssum[t] - s;
  for (int i = 0; i < CH; i++) {
    int idx = base + i;
    if (idx < NN) {
      row_ptr[idx] = run;
      cursor[idx] = run;
      run += deg[idx];
    }
  }
  if (t == 0) row_ptr[NN] = ssum[T - 1];
}

__global__ void k_scatter(const int* __restrict__ ei, int* __restrict__ cursor,
                          int* __restrict__ csr_src) {
  int e = blockIdx.x * blockDim.x + threadIdx.x;
  if (e < NE) {
    int d = ei[NE + e];
    int pos = atomicAdd(&cursor[d], 1);
    csr_src[pos] = ei[e];
  }
}

// ---------- weight transpose + bf16 convert: Wt[n][k] = W[k][n] ----------
__global__ void k_wt(const float* __restrict__ W, ushort* __restrict__ Wt, int K, int N) {
  __shared__ float tl[32][33];
  int bn = blockIdx.x * 32, bk = blockIdx.y * 32;
  int tx = threadIdx.x & 31, ty = threadIdx.x >> 5;
  for (int i = ty; i < 32; i += 8) tl[i][tx] = W[(size_t)(bk + i) * N + bn + tx];
  __syncthreads();
  for (int i = ty; i < 32; i += 8)
    Wt[(size_t)(bn + i) * K + bk + tx] = f2bf(tl[tx][i]);
}

// ---------- layer 1: collapsed attention vectors v_s/v_d[k][h] ----------
__global__ void k_vsd(const float* __restrict__ W1, const float* __restrict__ as1,
                      const float* __restrict__ ad1, float* __restrict__ vs,
                      float* __restrict__ vd) {
  int t = threadIdx.x;  // 128, 88 active
  if (t >= 88) return;
  int side = t & 1, kh = t >> 1;  // kh = k*4+h
  int k = kh >> 2, h = kh & 3;
  const float* av = side ? ad1 : as1;
  float s = 0.f;
  for (int c = 0; c < HID; c++) s += W1[k * 512 + h * HID + c] * av[h * HID + c];
  (side ? vd : vs)[kh] = s;
}

// ---------- layer 1: per-node attention scores from raw x ----------
__global__ void k_ax(const float* __restrict__ x, const float* __restrict__ vs,
                     const float* __restrict__ vd, float* __restrict__ asrc,
                     float* __restrict__ adst) {
  int n = blockIdx.x * blockDim.x + threadIdx.x;
  if (n >= NN) return;
  float xr[F_IN];
#pragma unroll
  for (int k = 0; k < F_IN; k++) xr[k] = x[n * F_IN + k];
  float s[4] = {}, dd[4] = {};
#pragma unroll
  for (int k = 0; k < F_IN; k++)
#pragma unroll
    for (int h = 0; h < 4; h++) {
      s[h] += xr[k] * vs[k * 4 + h];
      dd[h] += xr[k] * vd[k * 4 + h];
    }
  *(f32x4*)(asrc + n * 4) = f32x4{s[0], s[1], s[2], s[3]};
  *(f32x4*)(adst + n * 4) = f32x4{dd[0], dd[1], dd[2], dd[3]};
}

// ---------- layer 1: aggregate RAW x (11-dim, L2-resident) -> P[n][4][11] ----------
__global__ __launch_bounds__(256) void k_aggpre(
    const float* __restrict__ x, const float* __restrict__ asrc,
    const float* __restrict__ adst, const int* __restrict__ row_ptr,
    const int* __restrict__ csr_src, float* __restrict__ P) {
  const int CAP = 64;
  __shared__ int src_c[4][CAP];
  __shared__ float ea[4][CAP * 4];
  int t = threadIdx.x, lane = t & 63, wv = t >> 6;
  int d = blockIdx.x * 4 + wv;
  int start = row_ptr[d], deg = row_ptr[d + 1] - start;
  int dcap = min(deg, CAP);
  for (int i = lane; i < dcap; i += 64) src_c[wv][i] = csr_src[start + i];
  wave_fence();
  int hh = lane & 3;
  float adh = adst[d * 4 + hh];
  float m = MNEG, s = 0.f;
  int deg4 = deg * 4;
  for (int i = lane; i < deg4; i += 64) {
    int k = i >> 2;
    int sn = (k < CAP) ? src_c[wv][k] : csr_src[start + k];
    float v = lrelu(asrc[sn * 4 + hh] + adh);
    if (k < CAP) ea[wv][i] = v;
    float nm = fmaxf(m, v);
    s = s * __expf(m - nm) + __expf(v - nm);
    m = nm;
  }
#pragma unroll
  for (int off = 4; off < 64; off <<= 1) {
    float m2 = __shfl_xor(m, off);
    float s2 = __shfl_xor(s, off);
    float nm = fmaxf(m, m2);
    s = s * __expf(m - nm) + s2 * __expf(m2 - nm);
    m = nm;
  }
  float sinv = (s > 0.f) ? 1.f / s : 0.f;
  int dc4 = dcap * 4;
  for (int i = lane; i < dc4; i += 64) ea[wv][i] = __expf(ea[wv][i] - m) * sinv;
  wave_fence();
  // pass 2: lanes 0..43 own (h,k); unroll-4 edges for MLP
  int hq = lane / F_IN;
  int k = lane - hq * F_IN;
  int h = hq & 3;
  float mh = __shfl(m, h), sih = __shfl(sinv, h);
  float adh2 = adst[d * 4 + h];
  float acc = 0.f;
#define GETP(i, SN, A)                                                \
  do {                                                                \
    int kk_ = e + (i);                                                \
    if (kk_ < CAP) {                                                  \
      SN = src_c[wv][kk_];                                            \
      A = ea[wv][kk_ * 4 + h];                                        \
    } else {                                                          \
      SN = csr_src[start + kk_];                                      \
      A = __expf(lrelu(asrc[SN * 4 + h] + adh2) - mh) * sih;          \
    }                                                                 \
  } while (0)
  int e = 0;
  for (; e + 4 <= deg; e += 4) {
    int sn0, sn1, sn2, sn3;
    float a0, a1, a2, a3;
    GETP(0, sn0, a0);
    GETP(1, sn1, a1);
    GETP(2, sn2, a2);
    GETP(3, sn3, a3);
    float x0 = x[sn0 * F_IN + k];
    float x1 = x[sn1 * F_IN + k];
    float x2 = x[sn2 * F_IN + k];
    float x3 = x[sn3 * F_IN + k];
    acc += a0 * x0 + a1 * x1 + a2 * x2 + a3 * x3;
  }
  for (; e < deg; e++) {
    int sn;
    float a;
    GETP(0, sn, a);
    acc += a * x[sn * F_IN + k];
  }
#undef GETP
  if (lane < 44) P[(size_t)d * 44 + lane] = acc;
}

// ---------- layer 1: out = elu(P @ W1 + b1), 64 nodes/block ----------
__global__ __launch_bounds__(256) void k_gemm_l1(
    const float* __restrict__ P, const float* __restrict__ W1,
    const float* __restrict__ b1, ushort* __restrict__ out) {
  __shared__ float sW[F_IN * 512];
  __shared__ float sP[64][44];
  int t = threadIdx.x;
  for (int i = t; i < F_IN * 512; i += 256) sW[i] = W1[i];
  int n0 = blockIdx.x * 64;
  for (int i = t; i < 64 * 44; i += 256) {
    int nn = i / 44, kk = i % 44;
    sP[nn][kk] = (n0 + nn < NN) ? P[(size_t)(n0 + nn) * 44 + kk] : 0.f;
  }
  __syncthreads();
  int j0 = 2 * t;
  int h = j0 >> 7;
  float b0 = b1[j0], bb = b1[j0 + 1];
  float w0[F_IN], w1v[F_IN];
#pragma unroll
  for (int k = 0; k < F_IN; k++) {
    w0[k] = sW[k * 512 + j0];
    w1v[k] = sW[k * 512 + j0 + 1];
  }
  for (int nn = 0; nn < 64; nn++) {
    if (n0 + nn >= NN) break;
    float a0 = b0, a1 = bb;
#pragma unroll
    for (int k = 0; k < F_IN; k++) {
      float pv = sP[nn][h * F_IN + k];
      a0 += pv * w0[k];
      a1 += pv * w1v[k];
    }
    a0 = elu1(a0);
    a1 = elu1(a1);
    unsigned pk = (unsigned)f2bf(a0) | ((unsigned)f2bf(a1) << 16);
    *(unsigned*)(out + (size_t)(n0 + nn) * 512 + j0) = pk;
  }
}

// ---------- bf16 MFMA GEMM: C[M,N] = A[M,K] @ Bt[N,K]^T (pure, round-5) ----------
#define TM 128
#define TN 128
#define TK 64
__global__ __launch_bounds__(256) void k_mfma(const ushort* __restrict__ A,
                                              const ushort* __restrict__ Bt,
                                              ushort* __restrict__ C,
                                              int M, int N, int K) {
  __shared__ ushort lds[TM * TK + TN * TK];
  ushort* As = lds;
  ushort* Bs = lds + TM * TK;
  int tid = threadIdx.x;
  int lane = tid & 63, wv = tid >> 6;
  int wr = wv >> 1, wc = wv & 1;
  int bm0 = blockIdx.x * TM, bn0 = blockIdx.y * TN;
  int l15 = lane & 15, l4 = lane >> 4;
  f32x4 acc[4][4] = {};
  for (int k0 = 0; k0 < K; k0 += TK) {
#pragma unroll
    for (int it = 0; it < 4; ++it) {
      int chunk = it * 4 + wv;
      int pbase = chunk * 1024;
      int p = pbase + lane * 16;
      int prow = p >> 7;
      int lblk = ((p >> 4) & 7) ^ (prow & 7);
      int gr = bm0 + prow;
      gr = gr < M ? gr : M - 1;
      __builtin_amdgcn_global_load_lds(
          (const AS1 void*)(A + (size_t)gr * K + (k0 + lblk * 8)),
          (AS3 void*)((char*)As + pbase), 16, 0, 0);
      int gb = bn0 + prow;
      __builtin_amdgcn_global_load_lds(
          (const AS1 void*)(Bt + (size_t)gb * K + (k0 + lblk * 8)),
          (AS3 void*)((char*)Bs + pbase), 16, 0, 0);
    }
    __syncthreads();
#pragma unroll
    for (int kk = 0; kk < 2; ++kk) {
      int cb = kk * 4 + l4;
      short8 af[4], bfr[4];
#pragma unroll
      for (int m = 0; m < 4; ++m) {
        int row = wr * 64 + m * 16 + l15;
        af[m] = *(const short8*)((const char*)As + row * 128 + ((cb ^ (row & 7)) << 4));
      }
#pragma unroll
      for (int n = 0; n < 4; ++n) {
        int row = wc * 64 + n * 16 + l15;
        bfr[n] = *(const short8*)((const char*)Bs + row * 128 + ((cb ^ (row & 7)) << 4));
      }
#pragma unroll
      for (int m = 0; m < 4; ++m)
#pragma unroll
        for (int n = 0; n < 4; ++n)
          acc[m][n] = __builtin_amdgcn_mfma_f32_16x16x32_bf16(af[m], bfr[n], acc[m][n], 0, 0, 0);
    }
    __syncthreads();
  }
#pragma unroll
  for (int m = 0; m < 4; ++m) {
#pragma unroll
    for (int r = 0; r < 4; ++r) {
      int row = bm0 + wr * 64 + m * 16 + l4 * 4 + r;
      if (row < M) {
#pragma unroll
        for (int n = 0; n < 4; ++n) {
          int col = bn0 + wc * 64 + n * 16 + l15;
          C[(size_t)row * N + col] = f2bf(acc[m][n][r]);
        }
      }
    }
  }
}

// ---------- attention coefficients from transformed features (layers 2,3) ----------
template <int H>
__global__ void k_alpha(const ushort* __restrict__ h, const float* __restrict__ a_src,
                        const float* __restrict__ a_dst, float* __restrict__ asrc,
                        float* __restrict__ adst) {
  int t = threadIdx.x;  // 256
  int lane = t & 63;
  int n_g, h_g;
  if (H == 4) {
    n_g = blockIdx.x * 4 + (t >> 6);
    h_g = lane >> 4;
  } else {
    n_g = blockIdx.x * 16 + (t >> 4);
    h_g = 0;
  }
  if (n_g >= NN) return;
  int cl = lane & 15;
  short8 hv = *(const short8*)(h + (size_t)n_g * (H * 128) + h_g * 128 + cl * 8);
  const float* as = a_src + h_g * 128 + cl * 8;
  const float* ad = a_dst + h_g * 128 + cl * 8;
  float s1 = 0.f, s2 = 0.f;
#pragma unroll
  for (int j = 0; j < 8; j++) {
    float v = bf2f((ushort)hv[j]);
    s1 += v * as[j];
    s2 += v * ad[j];
  }
#pragma unroll
  for (int off = 1; off < 16; off <<= 1) {
    s1 += __shfl_xor(s1, off);
    s2 += __shfl_xor(s2, off);
  }
  if (cl == 0) {
    asrc[n_g * H + h_g] = s1;
    adst[n_g * H + h_g] = s2;
  }
}

// ---------- layer-2 aggregate: wave-per-node, H=4, unroll-4 gather ----------
__global__ __launch_bounds__(256) void k_agg4w(
    const ushort* __restrict__ h, const float* __restrict__ asrc,
    const float* __restrict__ adst, const int* __restrict__ row_ptr,
    const int* __restrict__ csr_src, const float* __restrict__ bias,
    ushort* __restrict__ out) {
  const int CAP = 64;
  __shared__ int src_c[4][CAP];
  __shared__ float ea[4][CAP * 4];
  int t = threadIdx.x, lane = t & 63, wv = t >> 6;
  int d = blockIdx.x * 4 + wv;
  int start = row_ptr[d], deg = row_ptr[d + 1] - start;
  int dcap = min(deg, CAP);
  for (int i = lane; i < dcap; i += 64) src_c[wv][i] = csr_src[start + i];
  wave_fence();
  int hh = lane & 3;
  float adh = adst[d * 4 + hh];
  float m = MNEG, s = 0.f;
  int deg4 = deg * 4;
  for (int i = lane; i < deg4; i += 64) {
    int k = i >> 2;
    int sn = (k < CAP) ? src_c[wv][k] : csr_src[start + k];
    float v = lrelu(asrc[sn * 4 + hh] + adh);
    if (k < CAP) ea[wv][i] = v;
    float nm = fmaxf(m, v);
    s = s * __expf(m - nm) + __expf(v - nm);
    m = nm;
  }
#pragma unroll
  for (int off = 4; off < 64; off <<= 1) {
    float m2 = __shfl_xor(m, off);
    float s2 = __shfl_xor(s, off);
    float nm = fmaxf(m, m2);
    s = s * __expf(m - nm) + s2 * __expf(m2 - nm);
    m = nm;
  }
  float sinv = (s > 0.f) ? 1.f / s : 0.f;
  int dc4 = dcap * 4;
  for (int i = lane; i < dc4; i += 64) ea[wv][i] = __expf(ea[wv][i] - m) * sinv;
  wave_fence();
  int hl = lane >> 4;
  float mh = __shfl(m, hl), sih = __shfl(sinv, hl);
  float adh2 = adst[d * 4 + hl];
#define GET4(i, SN, A)                                                \
  do {                                                                \
    int kk_ = k + (i);                                                \
    if (kk_ < CAP) {                                                  \
      SN = src_c[wv][kk_];                                            \
      A = ea[wv][kk_ * 4 + hl];                                       \
    } else {                                                          \
      SN = csr_src[start + kk_];                                      \
      A = __expf(lrelu(asrc[SN * 4 + hl] + adh2) - mh) * sih;         \
    }                                                                 \
  } while (0)
  float acc0[8] = {}, acc1[8] = {}, acc2[8] = {}, acc3[8] = {};
  int k = 0;
  for (; k + 4 <= deg; k += 4) {
    int sn0, sn1, sn2, sn3;
    float a0, a1, a2, a3;
    GET4(0, sn0, a0);
    GET4(1, sn1, a1);
    GET4(2, sn2, a2);
    GET4(3, sn3, a3);
    short8 v0 = *(const short8*)(h + (size_t)sn0 * 512 + lane * 8);
    short8 v1 = *(const short8*)(h + (size_t)sn1 * 512 + lane * 8);
    short8 v2 = *(const short8*)(h + (size_t)sn2 * 512 + lane * 8);
    short8 v3 = *(const short8*)(h + (size_t)sn3 * 512 + lane * 8);
#pragma unroll
    for (int j = 0; j < 8; j++) acc0[j] += a0 * bf2f((ushort)v0[j]);
#pragma unroll
    for (int j = 0; j < 8; j++) acc1[j] += a1 * bf2f((ushort)v1[j]);
#pragma unroll
    for (int j = 0; j < 8; j++) acc2[j] += a2 * bf2f((ushort)v2[j]);
#pragma unroll
    for (int j = 0; j < 8; j++) acc3[j] += a3 * bf2f((ushort)v3[j]);
  }
  for (; k < deg; k++) {
    int sn;
    float a;
    GET4(0, sn, a);
    short8 v0 = *(const short8*)(h + (size_t)sn * 512 + lane * 8);
#pragma unroll
    for (int j = 0; j < 8; j++) acc0[j] += a * bf2f((ushort)v0[j]);
  }
#undef GET4
  const float* bp = bias + lane * 8;
  unsigned pk[4];
#pragma unroll
  for (int j = 0; j < 4; j++) {
    float o0 = elu1(acc0[2 * j] + acc1[2 * j] + acc2[2 * j] + acc3[2 * j] + bp[2 * j]);
    float o1 = elu1(acc0[2 * j + 1] + acc1[2 * j + 1] + acc2[2 * j + 1] + acc3[2 * j + 1] +
                    bp[2 * j + 1]);
    pk[j] = (unsigned)f2bf(o0) | ((unsigned)f2bf(o1) << 16);
  }
  *(uint4*)(out + (size_t)d * 512 + lane * 8) = make_uint4(pk[0], pk[1], pk[2], pk[3]);
}

// ---------- layer-3 aggregate: wave-per-node, 16-lane x 4-edge-slot, 16B loads ----------
__global__ __launch_bounds__(256) void k_agg1w(
    const ushort* __restrict__ h, const float* __restrict__ asrc,
    const float* __restrict__ adst, const int* __restrict__ row_ptr,
    const int* __restrict__ csr_src, const float* __restrict__ bias,
    ushort* __restrict__ out) {
  const int CAP = 64;
  __shared__ int src_c[4][CAP];
  __shared__ float ea[4][CAP];
  int t = threadIdx.x, lane = t & 63, wv = t >> 6;
  int slot = lane >> 4, cl = lane & 15;
  int d = blockIdx.x * 4 + wv;
  int start = row_ptr[d], deg = row_ptr[d + 1] - start;
  int dcap = min(deg, CAP);
  for (int i = lane; i < dcap; i += 64) src_c[wv][i] = csr_src[start + i];
  wave_fence();
  float adh = adst[d];
  float m = MNEG, s = 0.f;
  for (int i = lane; i < deg; i += 64) {
    int sn = (i < CAP) ? src_c[wv][i] : csr_src[start + i];
    float v = lrelu(asrc[sn] + adh);
    if (i < CAP) ea[wv][i] = v;
    float nm = fmaxf(m, v);
    s = s * __expf(m - nm) + __expf(v - nm);
    m = nm;
  }
#pragma unroll
  for (int off = 1; off < 64; off <<= 1) {
    float m2 = __shfl_xor(m, off);
    float s2 = __shfl_xor(s, off);
    float nm = fmaxf(m, m2);
    s = s * __expf(m - nm) + s2 * __expf(m2 - nm);
    m = nm;
  }
  float sinv = (s > 0.f) ? 1.f / s : 0.f;
  for (int i = lane; i < dcap; i += 64) ea[wv][i] = __expf(ea[wv][i] - m) * sinv;
  wave_fence();
#define GET1(KK, SN, A)                                               \
  do {                                                                \
    if ((KK) < CAP) {                                                 \
      SN = src_c[wv][KK];                                             \
      A = ea[wv][KK];                                                 \
    } else {                                                          \
      SN = csr_src[start + (KK)];                                     \
      A = __expf(lrelu(asrc[SN] + adh) - m) * sinv;                   \
    }                                                                 \
  } while (0)
  // slot handles edges slot, slot+4, ... (4 in flight across slots, unroll-2 per slot)
  float acc0[8] = {}, acc1[8] = {};
  int k = slot;
  for (; k + 4 < deg; k += 8) {
    int sn0, sn1;
    float a0, a1;
    GET1(k, sn0, a0);
    GET1(k + 4, sn1, a1);
    short8 v0 = *(const short8*)(h + (size_t)sn0 * 128 + cl * 8);
    short8 v1 = *(const short8*)(h + (size_t)sn1 * 128 + cl * 8);
#pragma unroll
    for (int j = 0; j < 8; j++) acc0[j] += a0 * bf2f((ushort)v0[j]);
#pragma unroll
    for (int j = 0; j < 8; j++) acc1[j] += a1 * bf2f((ushort)v1[j]);
  }
  for (; k < deg; k += 4) {
    int sn;
    float a;
    GET1(k, sn, a);
    short8 v0 = *(const short8*)(h + (size_t)sn * 128 + cl * 8);
#pragma unroll
    for (int j = 0; j < 8; j++) acc0[j] += a * bf2f((ushort)v0[j]);
  }
#undef GET1
  // reduce across the 4 slots (lanes cl, cl+16, cl+32, cl+48)
#pragma unroll
  for (int j = 0; j < 8; j++) {
    float v = acc0[j] + acc1[j];
    v += __shfl_xor(v, 16);
    v += __shfl_xor(v, 32);
    acc0[j] = v;
  }
  if (slot == 0) {
    const float* bp = bias + cl * 8;
    unsigned pk[4];
#pragma unroll
    for (int j = 0; j < 4; j++) {
      float o0 = acc0[2 * j] + bp[2 * j];
      float o1 = acc0[2 * j + 1] + bp[2 * j + 1];
      pk[j] = (unsigned)f2bf(o0) | ((unsigned)f2bf(o1) << 16);
    }
    *(uint4*)(out + (size_t)d * 128 + cl * 8) = make_uint4(pk[0], pk[1], pk[2], pk[3]);
  }
}

// ---------- graph mean + heads ----------
__global__ __launch_bounds__(256) void k_colsum(const ushort* __restrict__ h3,
                                                float* __restrict__ gsum) {
  __shared__ float partial[16 * 128];
  int t = threadIdx.x;
  int rg = t >> 4, cl = t & 15;
  int nb = gridDim.x;
  int per = (NN + nb - 1) / nb;
  int r0 = blockIdx.x * per, r1 = min(NN, r0 + per);
  float acc[8] = {};
  for (int r = r0 + rg; r < r1; r += 16) {
    short8 hv = *(const short8*)(h3 + (size_t)r * 128 + cl * 8);
#pragma unroll
    for (int j = 0; j < 8; j++) acc[j] += bf2f((ushort)hv[j]);
  }
#pragma unroll
  for (int j = 0; j < 8; j++) partial[rg * 128 + cl * 8 + j] = acc[j];
  __syncthreads();
  if (t < 128) {
    float s = 0.f;
    for (int q = 0; q < 16; q++) s += partial[q * 128 + t];
    atomicAdd(&gsum[t], s);
  }
}

__global__ void k_head(const float* __restrict__ gsum, const ushort* __restrict__ h3,
                       const int* __restrict__ curp, const float* __restrict__ pw1,
                       const float* __restrict__ pb1, const float* __restrict__ pw2,
                       const float* __restrict__ pb2, const float* __restrict__ vw1,
                       const float* __restrict__ vb1, const float* __restrict__ vw2,
                       const float* __restrict__ vb2, float* __restrict__ outp) {
  __shared__ float comb[HID], ph[HID], vh[HID];
  int t = threadIdx.x;  // 128
  int cur = curp[0];
  comb[t] = gsum[t] * (1.f / NN) + bf2f(h3[(size_t)cur * HID + t]);
  __syncthreads();
  float accp = pb1[t], accv = vb1[t];
  for (int k = 0; k < HID; k++) {
    float cv = comb[k];
    accp += cv * pw1[k * HID + t];
    accv += cv * vw1[k * HID + t];
  }
  ph[t] = fmaxf(accp, 0.f);
  vh[t] = fmaxf(accv, 0.f);
  __syncthreads();
  if (t < 6) {
    float a = pb2[t];
    for (int k = 0; k < HID; k++) a += ph[k] * pw2[k * 6 + t];
    outp[t] = a;
  }
  if (t == 6) {
    float a = vb2[0];
    for (int k = 0; k < HID; k++) a += vh[k] * vw2[k];
    outp[6] = a;
  }
}

extern "C" void kernel_launch(void* const* d_in, const int* in_sizes, int n_in,
                              void* d_out, int out_size, void* d_ws, size_t ws_size,
                              hipStream_t stream) {
  const float* x = (const float*)d_in[0];
  const int* ei = (const int*)d_in[1];
  const int* cur = (const int*)d_in[2];
  const float* W1 = (const float*)d_in[3];
  const float* as1 = (const float*)d_in[4];
  const float* ad1 = (const float*)d_in[5];
  const float* b1 = (const float*)d_in[6];
  const float* W2 = (const float*)d_in[7];
  const float* as2 = (const float*)d_in[8];
  const float* ad2 = (const float*)d_in[9];
  const float* b2 = (const float*)d_in[10];
  const float* W3 = (const float*)d_in[11];
  const float* as3 = (const float*)d_in[12];
  const float* ad3 = (const float*)d_in[13];
  const float* b3 = (const float*)d_in[14];
  const float* pw1 = (const float*)d_in[15];
  const float* pb1 = (const float*)d_in[16];
  const float* pw2 = (const float*)d_in[17];
  const float* pb2 = (const float*)d_in[18];
  const float* vw1 = (const float*)d_in[19];
  const float* vb1 = (const float*)d_in[20];
  const float* vw2 = (const float*)d_in[21];
  const float* vb2 = (const float*)d_in[22];
  float* out = (float*)d_out;

  char* w = (char*)d_ws;
  ushort* G = (ushort*)w;    w += (size_t)NN * 512 * 2;
  ushort* Abuf = (ushort*)w; w += (size_t)NN * 512 * 2;
  ushort* Wt2 = (ushort*)w;  w += (size_t)512 * 512 * 2;
  ushort* Wt3 = (ushort*)w;  w += (size_t)128 * 512 * 2;
  float* P = (float*)w;      w += (size_t)NN * 44 * 4;
  float* asrc = (float*)w;   w += (size_t)NN * 4 * 4;
  float* adst = (float*)w;   w += (size_t)NN * 4 * 4;
  int* deg = (int*)w;        w += (size_t)NN * 4;
  int* cursor = (int*)w;     w += (size_t)NN * 4;
  int* row_ptr = (int*)w;    w += (size_t)(NN + 1) * 4;
  int* csr_src = (int*)w;    w += (size_t)NE * 4;
  float* gsum = (float*)w;   w += (size_t)HID * 4;
  float* vs = (float*)w;     w += 44 * 4;
  float* vd = (float*)w;     w += 44 * 4;

  hipMemsetAsync(deg, 0, NN * 4, stream);
  hipMemsetAsync(gsum, 0, HID * 4, stream);

  k_deg<<<(NE + 255) / 256, 256, 0, stream>>>(ei, deg);
  k_scan<<<1, 1024, 0, stream>>>(deg, row_ptr, cursor);
  k_scatter<<<(NE + 255) / 256, 256, 0, stream>>>(ei, cursor, csr_src);

  k_wt<<<dim3(512 / 32, 512 / 32), 256, 0, stream>>>(W2, Wt2, 512, 512);
  k_wt<<<dim3(128 / 32, 512 / 32), 256, 0, stream>>>(W3, Wt3, 512, 128);

  const int GB = (NN + TM - 1) / TM;  // 391

  // Layer 1 (pre-aggregation trick: aggregate raw x, then GEMM)
  k_vsd<<<1, 128, 0, stream>>>(W1, as1, ad1, vs, vd);
  k_ax<<<(NN + 255) / 256, 256, 0, stream>>>(x, vs, vd, asrc, adst);
  k_aggpre<<<NN / 4, 256, 0, stream>>>(x, asrc, adst, row_ptr, csr_src, P);
  k_gemm_l1<<<(NN + 63) / 64, 256, 0, stream>>>(P, W1, b1, Abuf);

  // Layer 2: bf16 MFMA, alpha, wave-per-node aggregate
  k_mfma<<<dim3(GB, 4), 256, 0, stream>>>(Abuf, Wt2, G, NN, 512, 512);
  k_alpha<4><<<(NN + 3) / 4, 256, 0, stream>>>(G, as2, ad2, asrc, adst);
  k_agg4w<<<NN / 4, 256, 0, stream>>>(G, asrc, adst, row_ptr, csr_src, b2, Abuf);

  // Layer 3: bf16 MFMA, alpha, wave-per-node aggregate
  k_mfma<<<dim3(GB, 1), 256, 0, stream>>>(Abuf, Wt3, G, NN, 128, 512);
  k_alpha<1><<<(NN + 15) / 16, 256, 0, stream>>>(G, as3, ad3, asrc, adst);
  k_agg1w<<<NN / 4, 256, 0, stream>>>(G, asrc, adst, row_ptr, csr_src, b3, Abuf);

  // Heads
  k_colsum<<<256, 256, 0, stream>>>(Abuf, gsum);
  k_head<<<1, 128, 0, stream>>>(gsum, Abuf, cur, pw1, pb1, pw2, pb2, vw1, vb1, vw2, vb2, out);
}

// Round 8
// 668.021 us; speedup vs baseline: 1.0179x; 1.0053x over previous
//
#include <hip/hip_runtime.h>
#include <math.h>

#define NN 50000
#define NE 800000
#define F_IN 11
#define HID 128
#define NEG_SLOPE 0.2f

typedef __attribute__((ext_vector_type(8))) short short8;
typedef __attribute__((ext_vector_type(4))) float f32x4;

__device__ __forceinline__ float bf2f(ushort u) {
  return __uint_as_float(((unsigned)u) << 16);
}
__device__ __forceinline__ ushort f2bf(float f) {
  unsigned u = __float_as_uint(f);
  return (ushort)((u + 0x7fff + ((u >> 16) & 1)) >> 16);
}
__device__ __forceinline__ float lrelu(float x) { return x > 0.f ? x : NEG_SLOPE * x; }
__device__ __forceinline__ float elu1(float x) { return x > 0.f ? x : expm1f(x); }

// finite "-inf": online-softmax merges of empty lanes must never form inf-inf=NaN
#define MNEG (-1e30f)

// order own-wave ds_writes before cross-lane ds_reads (no cross-wave sync needed)
__device__ __forceinline__ void wave_fence() {
  asm volatile("s_waitcnt lgkmcnt(0)" ::: "memory");
}

#define AS1 __attribute__((address_space(1)))
#define AS3 __attribute__((address_space(3)))

// ---------- CSR build ----------
__global__ void k_deg(const int* __restrict__ ei, int* __restrict__ deg) {
  int e = blockIdx.x * blockDim.x + threadIdx.x;
  if (e < NE) atomicAdd(&deg[ei[NE + e]], 1);
}

__global__ void k_scan(const int* __restrict__ deg, int* __restrict__ row_ptr,
                       int* __restrict__ cursor) {
  const int T = 1024;
  const int CH = (NN + T - 1) / T;
  __shared__ int ssum[T];
  int t = threadIdx.x;
  int base = t * CH;
  int s = 0;
  for (int i = 0; i < CH; i++) {
    int idx = base + i;
    if (idx < NN) s += deg[idx];
  }
  ssum[t] = s;
  __syncthreads();
  for (int off = 1; off < T; off <<= 1) {
    int v = (t >= off) ? ssum[t - off] : 0;
    __syncthreads();
    ssum[t] += v;
    __syncthreads();
  }
  int run = ssum[t] - s;
  for (int i = 0; i < CH; i++) {
    int idx = base + i;
    if (idx < NN) {
      row_ptr[idx] = run;
      cursor[idx] = run;
      run += deg[idx];
    }
  }
  if (t == 0) row_ptr[NN] = ssum[T - 1];
}

__global__ void k_scatter(const int* __restrict__ ei, int* __restrict__ cursor,
                          int* __restrict__ csr_src) {
  int e = blockIdx.x * blockDim.x + threadIdx.x;
  if (e < NE) {
    int d = ei[NE + e];
    int pos = atomicAdd(&cursor[d], 1);
    csr_src[pos] = ei[e];
  }
}

// ---------- weight transpose + bf16 convert: Wt[n][k] = W[k][n] ----------
__global__ void k_wt(const float* __restrict__ W, ushort* __restrict__ Wt, int K, int N) {
  __shared__ float tl[32][33];
  int bn = blockIdx.x * 32, bk = blockIdx.y * 32;
  int tx = threadIdx.x & 31, ty = threadIdx.x >> 5;
  for (int i = ty; i < 32; i += 8) tl[i][tx] = W[(size_t)(bk + i) * N + bn + tx];
  __syncthreads();
  for (int i = ty; i < 32; i += 8)
    Wt[(size_t)(bn + i) * K + bk + tx] = f2bf(tl[tx][i]);
}

// ---------- layer 1: collapsed attention vectors v_s/v_d[k][h] ----------
__global__ void k_vsd(const float* __restrict__ W1, const float* __restrict__ as1,
                      const float* __restrict__ ad1, float* __restrict__ vs,
                      float* __restrict__ vd) {
  int t = threadIdx.x;  // 128, 88 active
  if (t >= 88) return;
  int side = t & 1, kh = t >> 1;  // kh = k*4+h
  int k = kh >> 2, h = kh & 3;
  const float* av = side ? ad1 : as1;
  float s = 0.f;
  for (int c = 0; c < HID; c++) s += W1[k * 512 + h * HID + c] * av[h * HID + c];
  (side ? vd : vs)[kh] = s;
}

// ---------- layer 1: per-node attention scores from raw x ----------
__global__ void k_ax(const float* __restrict__ x, const float* __restrict__ vs,
                     const float* __restrict__ vd, float* __restrict__ asrc,
                     float* __restrict__ adst) {
  int n = blockIdx.x * blockDim.x + threadIdx.x;
  if (n >= NN) return;
  float xr[F_IN];
#pragma unroll
  for (int k = 0; k < F_IN; k++) xr[k] = x[n * F_IN + k];
  float s[4] = {}, dd[4] = {};
#pragma unroll
  for (int k = 0; k < F_IN; k++)
#pragma unroll
    for (int h = 0; h < 4; h++) {
      s[h] += xr[k] * vs[k * 4 + h];
      dd[h] += xr[k] * vd[k * 4 + h];
    }
  *(f32x4*)(asrc + n * 4) = f32x4{s[0], s[1], s[2], s[3]};
  *(f32x4*)(adst + n * 4) = f32x4{dd[0], dd[1], dd[2], dd[3]};
}

// ---------- layer 1: aggregate RAW x (11-dim, L2-resident) -> P[n][4][11] ----------
__global__ __launch_bounds__(256) void k_aggpre(
    const float* __restrict__ x, const float* __restrict__ asrc,
    const float* __restrict__ adst, const int* __restrict__ row_ptr,
    const int* __restrict__ csr_src, float* __restrict__ P) {
  const int CAP = 64;
  __shared__ int src_c[4][CAP];
  __shared__ float ea[4][CAP * 4];
  int t = threadIdx.x, lane = t & 63, wv = t >> 6;
  int d = blockIdx.x * 4 + wv;
  int start = row_ptr[d], deg = row_ptr[d + 1] - start;
  int dcap = min(deg, CAP);
  for (int i = lane; i < dcap; i += 64) src_c[wv][i] = csr_src[start + i];
  wave_fence();
  int hh = lane & 3;
  float adh = adst[d * 4 + hh];
  float m = MNEG, s = 0.f;
  int deg4 = deg * 4;
  for (int i = lane; i < deg4; i += 64) {
    int k = i >> 2;
    int sn = (k < CAP) ? src_c[wv][k] : csr_src[start + k];
    float v = lrelu(asrc[sn * 4 + hh] + adh);
    if (k < CAP) ea[wv][i] = v;
    float nm = fmaxf(m, v);
    s = s * __expf(m - nm) + __expf(v - nm);
    m = nm;
  }
#pragma unroll
  for (int off = 4; off < 64; off <<= 1) {
    float m2 = __shfl_xor(m, off);
    float s2 = __shfl_xor(s, off);
    float nm = fmaxf(m, m2);
    s = s * __expf(m - nm) + s2 * __expf(m2 - nm);
    m = nm;
  }
  float sinv = (s > 0.f) ? 1.f / s : 0.f;
  int dc4 = dcap * 4;
  for (int i = lane; i < dc4; i += 64) ea[wv][i] = __expf(ea[wv][i] - m) * sinv;
  wave_fence();
  // pass 2: lanes 0..43 own (h,k); unroll-4 edges for MLP
  int hq = lane / F_IN;
  int k = lane - hq * F_IN;
  int h = hq & 3;
  float mh = __shfl(m, h), sih = __shfl(sinv, h);
  float adh2 = adst[d * 4 + h];
  float acc = 0.f;
#define GETP(i, SN, A)                                                \
  do {                                                                \
    int kk_ = e + (i);                                                \
    if (kk_ < CAP) {                                                  \
      SN = src_c[wv][kk_];                                            \
      A = ea[wv][kk_ * 4 + h];                                        \
    } else {                                                          \
      SN = csr_src[start + kk_];                                      \
      A = __expf(lrelu(asrc[SN * 4 + h] + adh2) - mh) * sih;          \
    }                                                                 \
  } while (0)
  int e = 0;
  for (; e + 4 <= deg; e += 4) {
    int sn0, sn1, sn2, sn3;
    float a0, a1, a2, a3;
    GETP(0, sn0, a0);
    GETP(1, sn1, a1);
    GETP(2, sn2, a2);
    GETP(3, sn3, a3);
    float x0 = x[sn0 * F_IN + k];
    float x1 = x[sn1 * F_IN + k];
    float x2 = x[sn2 * F_IN + k];
    float x3 = x[sn3 * F_IN + k];
    acc += a0 * x0 + a1 * x1 + a2 * x2 + a3 * x3;
  }
  for (; e < deg; e++) {
    int sn;
    float a;
    GETP(0, sn, a);
    acc += a * x[sn * F_IN + k];
  }
#undef GETP
  if (lane < 44) P[(size_t)d * 44 + lane] = acc;
}

// ---------- layer 1: out = elu(P @ W1 + b1), 64 nodes/block ----------
__global__ __launch_bounds__(256) void k_gemm_l1(
    const float* __restrict__ P, const float* __restrict__ W1,
    const float* __restrict__ b1, ushort* __restrict__ out) {
  __shared__ float sW[F_IN * 512];
  __shared__ float sP[64][44];
  int t = threadIdx.x;
  for (int i = t; i < F_IN * 512; i += 256) sW[i] = W1[i];
  int n0 = blockIdx.x * 64;
  for (int i = t; i < 64 * 44; i += 256) {
    int nn = i / 44, kk = i % 44;
    sP[nn][kk] = (n0 + nn < NN) ? P[(size_t)(n0 + nn) * 44 + kk] : 0.f;
  }
  __syncthreads();
  int j0 = 2 * t;
  int h = j0 >> 7;
  float b0 = b1[j0], bb = b1[j0 + 1];
  float w0[F_IN], w1v[F_IN];
#pragma unroll
  for (int k = 0; k < F_IN; k++) {
    w0[k] = sW[k * 512 + j0];
    w1v[k] = sW[k * 512 + j0 + 1];
  }
  for (int nn = 0; nn < 64; nn++) {
    if (n0 + nn >= NN) break;
    float a0 = b0, a1 = bb;
#pragma unroll
    for (int k = 0; k < F_IN; k++) {
      float pv = sP[nn][h * F_IN + k];
      a0 += pv * w0[k];
      a1 += pv * w1v[k];
    }
    a0 = elu1(a0);
    a1 = elu1(a1);
    unsigned pk = (unsigned)f2bf(a0) | ((unsigned)f2bf(a1) << 16);
    *(unsigned*)(out + (size_t)(n0 + nn) * 512 + j0) = pk;
  }
}

// ---------- bf16 MFMA GEMM: C[M,N] = A[M,K] @ Bt[N,K]^T ----------
// 1D grid + bijective XCD-chunk swizzle (m204): consecutive lids share the
// A-panel (bm), so each XCD's L2 fetches A once instead of H times.
#define TM 128
#define TN 128
#define TK 64
__global__ __launch_bounds__(256) void k_mfma(const ushort* __restrict__ A,
                                              const ushort* __restrict__ Bt,
                                              ushort* __restrict__ C,
                                              int M, int N, int K, int H) {
  __shared__ ushort lds[TM * TK + TN * TK];
  ushort* As = lds;
  ushort* Bs = lds + TM * TK;
  int tid = threadIdx.x;
  int lane = tid & 63, wv = tid >> 6;
  int wr = wv >> 1, wc = wv & 1;
  int nwg = gridDim.x;
  int q = nwg >> 3, rr = nwg & 7;
  int xcd = blockIdx.x & 7, off8 = blockIdx.x >> 3;
  int lid = (xcd < rr ? xcd * (q + 1) : rr * (q + 1) + (xcd - rr) * q) + off8;
  int bm = lid / H, hy = lid - bm * H;
  int bm0 = bm * TM, bn0 = hy * TN;
  int l15 = lane & 15, l4 = lane >> 4;
  f32x4 acc[4][4] = {};
  for (int k0 = 0; k0 < K; k0 += TK) {
#pragma unroll
    for (int it = 0; it < 4; ++it) {
      int chunk = it * 4 + wv;
      int pbase = chunk * 1024;
      int p = pbase + lane * 16;
      int prow = p >> 7;
      int lblk = ((p >> 4) & 7) ^ (prow & 7);
      int gr = bm0 + prow;
      gr = gr < M ? gr : M - 1;
      __builtin_amdgcn_global_load_lds(
          (const AS1 void*)(A + (size_t)gr * K + (k0 + lblk * 8)),
          (AS3 void*)((char*)As + pbase), 16, 0, 0);
      int gb = bn0 + prow;
      __builtin_amdgcn_global_load_lds(
          (const AS1 void*)(Bt + (size_t)gb * K + (k0 + lblk * 8)),
          (AS3 void*)((char*)Bs + pbase), 16, 0, 0);
    }
    __syncthreads();
#pragma unroll
    for (int kk = 0; kk < 2; ++kk) {
      int cb = kk * 4 + l4;
      short8 af[4], bfr[4];
#pragma unroll
      for (int m = 0; m < 4; ++m) {
        int row = wr * 64 + m * 16 + l15;
        af[m] = *(const short8*)((const char*)As + row * 128 + ((cb ^ (row & 7)) << 4));
      }
#pragma unroll
      for (int n = 0; n < 4; ++n) {
        int row = wc * 64 + n * 16 + l15;
        bfr[n] = *(const short8*)((const char*)Bs + row * 128 + ((cb ^ (row & 7)) << 4));
      }
#pragma unroll
      for (int m = 0; m < 4; ++m)
#pragma unroll
        for (int n = 0; n < 4; ++n)
          acc[m][n] = __builtin_amdgcn_mfma_f32_16x16x32_bf16(af[m], bfr[n], acc[m][n], 0, 0, 0);
    }
    __syncthreads();
  }
#pragma unroll
  for (int m = 0; m < 4; ++m) {
#pragma unroll
    for (int r = 0; r < 4; ++r) {
      int row = bm0 + wr * 64 + m * 16 + l4 * 4 + r;
      if (row < M) {
#pragma unroll
        for (int n = 0; n < 4; ++n) {
          int col = bn0 + wc * 64 + n * 16 + l15;
          C[(size_t)row * N + col] = f2bf(acc[m][n][r]);
        }
      }
    }
  }
}

// ---------- attention coefficients from transformed features (layers 2,3) ----------
template <int H>
__global__ void k_alpha(const ushort* __restrict__ h, const float* __restrict__ a_src,
                        const float* __restrict__ a_dst, float* __restrict__ asrc,
                        float* __restrict__ adst) {
  int t = threadIdx.x;  // 256
  int lane = t & 63;
  int n_g, h_g;
  if (H == 4) {
    n_g = blockIdx.x * 4 + (t >> 6);
    h_g = lane >> 4;
  } else {
    n_g = blockIdx.x * 16 + (t >> 4);
    h_g = 0;
  }
  if (n_g >= NN) return;
  int cl = lane & 15;
  short8 hv = *(const short8*)(h + (size_t)n_g * (H * 128) + h_g * 128 + cl * 8);
  const float* as = a_src + h_g * 128 + cl * 8;
  const float* ad = a_dst + h_g * 128 + cl * 8;
  float s1 = 0.f, s2 = 0.f;
#pragma unroll
  for (int j = 0; j < 8; j++) {
    float v = bf2f((ushort)hv[j]);
    s1 += v * as[j];
    s2 += v * ad[j];
  }
#pragma unroll
  for (int off = 1; off < 16; off <<= 1) {
    s1 += __shfl_xor(s1, off);
    s2 += __shfl_xor(s2, off);
  }
  if (cl == 0) {
    asrc[n_g * H + h_g] = s1;
    adst[n_g * H + h_g] = s2;
  }
}

// ---------- layer-2 aggregate: wave-per-node, H=4, unroll-2 gather ----------
// (unroll-2 is the sweet spot: 28 VGPR / ~86% occupancy; unroll-4 was 48 VGPR
//  / 51% occupancy and 10us slower — round-7 post-mortem)
__global__ __launch_bounds__(256) void k_agg4w(
    const ushort* __restrict__ h, const float* __restrict__ asrc,
    const float* __restrict__ adst, const int* __restrict__ row_ptr,
    const int* __restrict__ csr_src, const float* __restrict__ bias,
    ushort* __restrict__ out) {
  const int CAP = 64;
  __shared__ int src_c[4][CAP];
  __shared__ float ea[4][CAP * 4];
  int t = threadIdx.x, lane = t & 63, wv = t >> 6;
  int d = blockIdx.x * 4 + wv;
  int start = row_ptr[d], deg = row_ptr[d + 1] - start;
  int dcap = min(deg, CAP);
  for (int i = lane; i < dcap; i += 64) src_c[wv][i] = csr_src[start + i];
  wave_fence();
  int hh = lane & 3;
  float adh = adst[d * 4 + hh];
  float m = MNEG, s = 0.f;
  int deg4 = deg * 4;
  for (int i = lane; i < deg4; i += 64) {
    int k = i >> 2;
    int sn = (k < CAP) ? src_c[wv][k] : csr_src[start + k];
    float v = lrelu(asrc[sn * 4 + hh] + adh);
    if (k < CAP) ea[wv][i] = v;
    float nm = fmaxf(m, v);
    s = s * __expf(m - nm) + __expf(v - nm);
    m = nm;
  }
#pragma unroll
  for (int off = 4; off < 64; off <<= 1) {
    float m2 = __shfl_xor(m, off);
    float s2 = __shfl_xor(s, off);
    float nm = fmaxf(m, m2);
    s = s * __expf(m - nm) + s2 * __expf(m2 - nm);
    m = nm;
  }
  float sinv = (s > 0.f) ? 1.f / s : 0.f;
  int dc4 = dcap * 4;
  for (int i = lane; i < dc4; i += 64) ea[wv][i] = __expf(ea[wv][i] - m) * sinv;
  wave_fence();
  int hl = lane >> 4;
  float mh = __shfl(m, hl), sih = __shfl(sinv, hl);
  float adh2 = adst[d * 4 + hl];
  float acc0[8] = {}, acc1[8] = {};
  int k = 0;
  for (; k + 2 <= deg; k += 2) {
    int sn0, sn1;
    float a0, a1;
    if (k < CAP) {
      sn0 = src_c[wv][k];
      a0 = ea[wv][k * 4 + hl];
    } else {
      sn0 = csr_src[start + k];
      a0 = __expf(lrelu(asrc[sn0 * 4 + hl] + adh2) - mh) * sih;
    }
    if (k + 1 < CAP) {
      sn1 = src_c[wv][k + 1];
      a1 = ea[wv][(k + 1) * 4 + hl];
    } else {
      sn1 = csr_src[start + k + 1];
      a1 = __expf(lrelu(asrc[sn1 * 4 + hl] + adh2) - mh) * sih;
    }
    short8 v0 = *(const short8*)(h + (size_t)sn0 * 512 + lane * 8);
    short8 v1 = *(const short8*)(h + (size_t)sn1 * 512 + lane * 8);
#pragma unroll
    for (int j = 0; j < 8; j++) acc0[j] += a0 * bf2f((ushort)v0[j]);
#pragma unroll
    for (int j = 0; j < 8; j++) acc1[j] += a1 * bf2f((ushort)v1[j]);
  }
  if (k < deg) {
    int sn;
    float a;
    if (k < CAP) {
      sn = src_c[wv][k];
      a = ea[wv][k * 4 + hl];
    } else {
      sn = csr_src[start + k];
      a = __expf(lrelu(asrc[sn * 4 + hl] + adh2) - mh) * sih;
    }
    short8 v0 = *(const short8*)(h + (size_t)sn * 512 + lane * 8);
#pragma unroll
    for (int j = 0; j < 8; j++) acc0[j] += a * bf2f((ushort)v0[j]);
  }
  const float* bp = bias + lane * 8;
  unsigned pk[4];
#pragma unroll
  for (int j = 0; j < 4; j++) {
    float o0 = elu1(acc0[2 * j] + acc1[2 * j] + bp[2 * j]);
    float o1 = elu1(acc0[2 * j + 1] + acc1[2 * j + 1] + bp[2 * j + 1]);
    pk[j] = (unsigned)f2bf(o0) | ((unsigned)f2bf(o1) << 16);
  }
  *(uint4*)(out + (size_t)d * 512 + lane * 8) = make_uint4(pk[0], pk[1], pk[2], pk[3]);
}

// ---------- layer-3 aggregate: wave-per-node, 16-lane x 4-edge-slot, 16B loads ----------
__global__ __launch_bounds__(256) void k_agg1w(
    const ushort* __restrict__ h, const float* __restrict__ asrc,
    const float* __restrict__ adst, const int* __restrict__ row_ptr,
    const int* __restrict__ csr_src, const float* __restrict__ bias,
    ushort* __restrict__ out) {
  const int CAP = 64;
  __shared__ int src_c[4][CAP];
  __shared__ float ea[4][CAP];
  int t = threadIdx.x, lane = t & 63, wv = t >> 6;
  int slot = lane >> 4, cl = lane & 15;
  int d = blockIdx.x * 4 + wv;
  int start = row_ptr[d], deg = row_ptr[d + 1] - start;
  int dcap = min(deg, CAP);
  for (int i = lane; i < dcap; i += 64) src_c[wv][i] = csr_src[start + i];
  wave_fence();
  float adh = adst[d];
  float m = MNEG, s = 0.f;
  for (int i = lane; i < deg; i += 64) {
    int sn = (i < CAP) ? src_c[wv][i] : csr_src[start + i];
    float v = lrelu(asrc[sn] + adh);
    if (i < CAP) ea[wv][i] = v;
    float nm = fmaxf(m, v);
    s = s * __expf(m - nm) + __expf(v - nm);
    m = nm;
  }
#pragma unroll
  for (int off = 1; off < 64; off <<= 1) {
    float m2 = __shfl_xor(m, off);
    float s2 = __shfl_xor(s, off);
    float nm = fmaxf(m, m2);
    s = s * __expf(m - nm) + s2 * __expf(m2 - nm);
    m = nm;
  }
  float sinv = (s > 0.f) ? 1.f / s : 0.f;
  for (int i = lane; i < dcap; i += 64) ea[wv][i] = __expf(ea[wv][i] - m) * sinv;
  wave_fence();
#define GET1(KK, SN, A)                                               \
  do {                                                                \
    if ((KK) < CAP) {                                                 \
      SN = src_c[wv][KK];                                             \
      A = ea[wv][KK];                                                 \
    } else {                                                          \
      SN = csr_src[start + (KK)];                                     \
      A = __expf(lrelu(asrc[SN] + adh) - m) * sinv;                   \
    }                                                                 \
  } while (0)
  float acc0[8] = {}, acc1[8] = {};
  int k = slot;
  for (; k + 4 < deg; k += 8) {
    int sn0, sn1;
    float a0, a1;
    GET1(k, sn0, a0);
    GET1(k + 4, sn1, a1);
    short8 v0 = *(const short8*)(h + (size_t)sn0 * 128 + cl * 8);
    short8 v1 = *(const short8*)(h + (size_t)sn1 * 128 + cl * 8);
#pragma unroll
    for (int j = 0; j < 8; j++) acc0[j] += a0 * bf2f((ushort)v0[j]);
#pragma unroll
    for (int j = 0; j < 8; j++) acc1[j] += a1 * bf2f((ushort)v1[j]);
  }
  for (; k < deg; k += 4) {
    int sn;
    float a;
    GET1(k, sn, a);
    short8 v0 = *(const short8*)(h + (size_t)sn * 128 + cl * 8);
#pragma unroll
    for (int j = 0; j < 8; j++) acc0[j] += a * bf2f((ushort)v0[j]);
  }
#undef GET1
#pragma unroll
  for (int j = 0; j < 8; j++) {
    float v = acc0[j] + acc1[j];
    v += __shfl_xor(v, 16);
    v += __shfl_xor(v, 32);
    acc0[j] = v;
  }
  if (slot == 0) {
    const float* bp = bias + cl * 8;
    unsigned pk[4];
#pragma unroll
    for (int j = 0; j < 4; j++) {
      float o0 = acc0[2 * j] + bp[2 * j];
      float o1 = acc0[2 * j + 1] + bp[2 * j + 1];
      pk[j] = (unsigned)f2bf(o0) | ((unsigned)f2bf(o1) << 16);
    }
    *(uint4*)(out + (size_t)d * 128 + cl * 8) = make_uint4(pk[0], pk[1], pk[2], pk[3]);
  }
}

// ---------- graph mean + heads ----------
__global__ __launch_bounds__(256) void k_colsum(const ushort* __restrict__ h3,
                                                float* __restrict__ gsum) {
  __shared__ float partial[16 * 128];
  int t = threadIdx.x;
  int rg = t >> 4, cl = t & 15;
  int nb = gridDim.x;
  int per = (NN + nb - 1) / nb;
  int r0 = blockIdx.x * per, r1 = min(NN, r0 + per);
  float acc[8] = {};
  for (int r = r0 + rg; r < r1; r += 16) {
    short8 hv = *(const short8*)(h3 + (size_t)r * 128 + cl * 8);
#pragma unroll
    for (int j = 0; j < 8; j++) acc[j] += bf2f((ushort)hv[j]);
  }
#pragma unroll
  for (int j = 0; j < 8; j++) partial[rg * 128 + cl * 8 + j] = acc[j];
  __syncthreads();
  if (t < 128) {
    float s = 0.f;
    for (int q = 0; q < 16; q++) s += partial[q * 128 + t];
    atomicAdd(&gsum[t], s);
  }
}

__global__ void k_head(const float* __restrict__ gsum, const ushort* __restrict__ h3,
                       const int* __restrict__ curp, const float* __restrict__ pw1,
                       const float* __restrict__ pb1, const float* __restrict__ pw2,
                       const float* __restrict__ pb2, const float* __restrict__ vw1,
                       const float* __restrict__ vb1, const float* __restrict__ vw2,
                       const float* __restrict__ vb2, float* __restrict__ outp) {
  __shared__ float comb[HID], ph[HID], vh[HID];
  int t = threadIdx.x;  // 128
  int cur = curp[0];
  comb[t] = gsum[t] * (1.f / NN) + bf2f(h3[(size_t)cur * HID + t]);
  __syncthreads();
  float accp = pb1[t], accv = vb1[t];
  for (int k = 0; k < HID; k++) {
    float cv = comb[k];
    accp += cv * pw1[k * HID + t];
    accv += cv * vw1[k * HID + t];
  }
  ph[t] = fmaxf(accp, 0.f);
  vh[t] = fmaxf(accv, 0.f);
  __syncthreads();
  if (t < 6) {
    float a = pb2[t];
    for (int k = 0; k < HID; k++) a += ph[k] * pw2[k * 6 + t];
    outp[t] = a;
  }
  if (t == 6) {
    float a = vb2[0];
    for (int k = 0; k < HID; k++) a += vh[k] * vw2[k];
    outp[6] = a;
  }
}

extern "C" void kernel_launch(void* const* d_in, const int* in_sizes, int n_in,
                              void* d_out, int out_size, void* d_ws, size_t ws_size,
                              hipStream_t stream) {
  const float* x = (const float*)d_in[0];
  const int* ei = (const int*)d_in[1];
  const int* cur = (const int*)d_in[2];
  const float* W1 = (const float*)d_in[3];
  const float* as1 = (const float*)d_in[4];
  const float* ad1 = (const float*)d_in[5];
  const float* b1 = (const float*)d_in[6];
  const float* W2 = (const float*)d_in[7];
  const float* as2 = (const float*)d_in[8];
  const float* ad2 = (const float*)d_in[9];
  const float* b2 = (const float*)d_in[10];
  const float* W3 = (const float*)d_in[11];
  const float* as3 = (const float*)d_in[12];
  const float* ad3 = (const float*)d_in[13];
  const float* b3 = (const float*)d_in[14];
  const float* pw1 = (const float*)d_in[15];
  const float* pb1 = (const float*)d_in[16];
  const float* pw2 = (const float*)d_in[17];
  const float* pb2 = (const float*)d_in[18];
  const float* vw1 = (const float*)d_in[19];
  const float* vb1 = (const float*)d_in[20];
  const float* vw2 = (const float*)d_in[21];
  const float* vb2 = (const float*)d_in[22];
  float* out = (float*)d_out;

  char* w = (char*)d_ws;
  ushort* G = (ushort*)w;    w += (size_t)NN * 512 * 2;
  ushort* Abuf = (ushort*)w; w += (size_t)NN * 512 * 2;
  ushort* Wt2 = (ushort*)w;  w += (size_t)512 * 512 * 2;
  ushort* Wt3 = (ushort*)w;  w += (size_t)128 * 512 * 2;
  float* P = (float*)w;      w += (size_t)NN * 44 * 4;
  float* asrc = (float*)w;   w += (size_t)NN * 4 * 4;
  float* adst = (float*)w;   w += (size_t)NN * 4 * 4;
  int* deg = (int*)w;        w += (size_t)NN * 4;
  int* cursor = (int*)w;     w += (size_t)NN * 4;
  int* row_ptr = (int*)w;    w += (size_t)(NN + 1) * 4;
  int* csr_src = (int*)w;    w += (size_t)NE * 4;
  float* gsum = (float*)w;   w += (size_t)HID * 4;
  float* vs = (float*)w;     w += 44 * 4;
  float* vd = (float*)w;     w += 44 * 4;

  hipMemsetAsync(deg, 0, NN * 4, stream);
  hipMemsetAsync(gsum, 0, HID * 4, stream);

  k_deg<<<(NE + 255) / 256, 256, 0, stream>>>(ei, deg);
  k_scan<<<1, 1024, 0, stream>>>(deg, row_ptr, cursor);
  k_scatter<<<(NE + 255) / 256, 256, 0, stream>>>(ei, cursor, csr_src);

  k_wt<<<dim3(512 / 32, 512 / 32), 256, 0, stream>>>(W2, Wt2, 512, 512);
  k_wt<<<dim3(128 / 32, 512 / 32), 256, 0, stream>>>(W3, Wt3, 512, 128);

  const int GB = (NN + TM - 1) / TM;  // 391

  // Layer 1 (pre-aggregation trick: aggregate raw x, then GEMM)
  k_vsd<<<1, 128, 0, stream>>>(W1, as1, ad1, vs, vd);
  k_ax<<<(NN + 255) / 256, 256, 0, stream>>>(x, vs, vd, asrc, adst);
  k_aggpre<<<NN / 4, 256, 0, stream>>>(x, asrc, adst, row_ptr, csr_src, P);
  k_gemm_l1<<<(NN + 63) / 64, 256, 0, stream>>>(P, W1, b1, Abuf);

  // Layer 2: bf16 MFMA (XCD-chunk swizzled), alpha, wave-per-node aggregate
  k_mfma<<<GB * 4, 256, 0, stream>>>(Abuf, Wt2, G, NN, 512, 512, 4);
  k_alpha<4><<<(NN + 3) / 4, 256, 0, stream>>>(G, as2, ad2, asrc, adst);
  k_agg4w<<<NN / 4, 256, 0, stream>>>(G, asrc, adst, row_ptr, csr_src, b2, Abuf);

  // Layer 3: bf16 MFMA, alpha, wave-per-node aggregate
  k_mfma<<<GB, 256, 0, stream>>>(Abuf, Wt3, G, NN, 128, 512, 1);
  k_alpha<1><<<(NN + 15) / 16, 256, 0, stream>>>(G, as3, ad3, asrc, adst);
  k_agg1w<<<NN / 4, 256, 0, stream>>>(G, asrc, adst, row_ptr, csr_src, b3, Abuf);

  // Heads
  k_colsum<<<256, 256, 0, stream>>>(Abuf, gsum);
  k_head<<<1, 128, 0, stream>>>(gsum, Abuf, cur, pw1, pb1, pw2, pb2, vw1, vb1, vw2, vb2, out);
}